// Round 1
// baseline (433.995 us; speedup 1.0000x reference)
//
#include <hip/hip_runtime.h>
#include <hip/hip_bf16.h>
#include <math.h>

typedef unsigned short ushort_t;
typedef __bf16 bf16x8 __attribute__((ext_vector_type(8)));
typedef float f32x4 __attribute__((ext_vector_type(4)));

#define HIDDEN 896
#define NQH 14
#define NKVH 2
#define HD 64
#define SEQ 2048
#define NBATCH 4

__device__ inline ushort_t f2bf(float x) {
  union { float f; unsigned u; } c; c.f = x;
  unsigned r = c.u + 0x7FFFu + ((c.u >> 16) & 1u);
  return (ushort_t)(r >> 16);
}

__device__ inline bf16x8 ldfrag(const ushort_t* p) {
  return *reinterpret_cast<const bf16x8*>(p);
}

__device__ inline void async16(const ushort_t* g, ushort_t* l) {
  __builtin_amdgcn_global_load_lds(
      (const __attribute__((address_space(1))) void*)g,
      (__attribute__((address_space(3))) void*)l, 16, 0, 0);
}

// ---------------- prep kernels ----------------

__global__ void k_convert(const float* __restrict__ in, ushort_t* __restrict__ out, int n4) {
  int i = blockIdx.x * blockDim.x + threadIdx.x;
  if (i >= n4) return;
  float4 v = reinterpret_cast<const float4*>(in)[i];
  ushort4 o;
  o.x = f2bf(v.x); o.y = f2bf(v.y); o.z = f2bf(v.z); o.w = f2bf(v.w);
  reinterpret_cast<ushort4*>(out)[i] = o;
}

// in [K][N] f32 -> out [N][K] bf16
__global__ void k_transpose(const float* __restrict__ in, ushort_t* __restrict__ out, int K, int N) {
  __shared__ float tile[32][33];
  int k0 = blockIdx.y * 32, n0 = blockIdx.x * 32;
  for (int r = threadIdx.y; r < 32; r += 8) {
    int k = k0 + r, n = n0 + threadIdx.x;
    tile[r][threadIdx.x] = (k < K && n < N) ? in[(size_t)k * N + n] : 0.f;
  }
  __syncthreads();
  for (int r = threadIdx.y; r < 32; r += 8) {
    int n = n0 + r, k = k0 + threadIdx.x;
    if (n < N && k < K) out[(size_t)n * K + k] = f2bf(tile[threadIdx.x][r]);
  }
}

// ---------------- QKV projection + RoPE ----------------
// grid: (18, 64). nt 0..13 -> Q head nt; 14..15 -> K kvh; 16..17 -> V kvh.
__global__ __launch_bounds__(256) void k_qkv(
    const ushort_t* __restrict__ hb,
    const ushort_t* __restrict__ wqT,
    const ushort_t* __restrict__ wkT,
    const ushort_t* __restrict__ wvT,
    const int* __restrict__ pos_ids,
    ushort_t* __restrict__ Qg,
    ushort_t* __restrict__ Kg,
    ushort_t* __restrict__ Vtg) {
  __shared__ ushort_t sa[128 * 32];
  __shared__ ushort_t sb[64 * 32];
  __shared__ float cbuf[128 * 64];

  const int nt = blockIdx.x;
  const int m0 = blockIdx.y * 128;
  const int tid = threadIdx.x;
  const int wave = tid >> 6, lane = tid & 63;
  const int l15 = lane & 15, quad = lane >> 4;
  const int wm = wave >> 1, wn = wave & 1;

  const ushort_t* wsrc; int nsrc0;
  if (nt < 14)      { wsrc = wqT; nsrc0 = nt * 64; }
  else if (nt < 16) { wsrc = wkT; nsrc0 = (nt - 14) * 64; }
  else              { wsrc = wvT; nsrc0 = (nt - 16) * 64; }

  f32x4 acc[4][2];
  const f32x4 z4 = {0.f, 0.f, 0.f, 0.f};
#pragma unroll
  for (int a = 0; a < 4; ++a)
#pragma unroll
    for (int b = 0; b < 2; ++b) acc[a][b] = z4;

  for (int kt = 0; kt < 28; ++kt) {
    const int k0 = kt * 32;
    __syncthreads();
#pragma unroll
    for (int i = 0; i < 2; ++i) {
      int c = wave * 128 + i * 64 + lane;
      async16(hb + (size_t)(m0 + (c >> 2)) * HIDDEN + k0 + (c & 3) * 8,
              sa + (size_t)(wave * 128 + i * 64) * 8);
    }
    {
      int c = wave * 64 + lane;
      async16(wsrc + (size_t)(nsrc0 + (c >> 2)) * HIDDEN + k0 + (c & 3) * 8,
              sb + (size_t)(wave * 64) * 8);
    }
    __syncthreads();
    bf16x8 bf0 = ldfrag(sb + ((wn * 32 + l15) * 32 + quad * 8));
    bf16x8 bf1 = ldfrag(sb + ((wn * 32 + 16 + l15) * 32 + quad * 8));
#pragma unroll
    for (int mb = 0; mb < 4; ++mb) {
      bf16x8 af = ldfrag(sa + ((wm * 64 + mb * 16 + l15) * 32 + quad * 8));
      acc[mb][0] = __builtin_amdgcn_mfma_f32_16x16x32_bf16(af, bf0, acc[mb][0], 0, 0, 0);
      acc[mb][1] = __builtin_amdgcn_mfma_f32_16x16x32_bf16(af, bf1, acc[mb][1], 0, 0, 0);
    }
  }

  __syncthreads();
#pragma unroll
  for (int mb = 0; mb < 4; ++mb)
#pragma unroll
    for (int nb = 0; nb < 2; ++nb)
#pragma unroll
      for (int r = 0; r < 4; ++r)
        cbuf[(wm * 64 + mb * 16 + quad * 4 + r) * 64 + wn * 32 + nb * 16 + l15] = acc[mb][nb][r];
  __syncthreads();

  if (nt < 16) {
    // RoPE + store (Q or K)
    for (int p = tid; p < 128 * 32; p += 256) {
      int row = p >> 5, d = p & 31;
      int token = m0 + row;
      int b = token >> 11, s = token & 2047;
      int pos = pos_ids[token];
      float x0 = cbuf[row * 64 + d];
      float x1 = cbuf[row * 64 + d + 32];
      // inv_freq = 10000^(-d/32) = 2^(-d*log2(10000)/32)
      float inv = exp2f(-(float)d * 0.41524101186092596f);
      float ang = (float)pos * inv;
      float sn, cn;
      sincosf(ang, &sn, &cn);
      float y0 = x0 * cn - x1 * sn;
      float y1 = x1 * cn + x0 * sn;
      if (nt < 14) {
        size_t base = ((size_t)(b * NQH + nt) * SEQ + s) * HD;
        Qg[base + d]      = f2bf(y0);
        Qg[base + d + 32] = f2bf(y1);
      } else {
        size_t base = ((size_t)(b * NKVH + (nt - 14)) * SEQ + s) * HD;
        Kg[base + d]      = f2bf(y0);
        Kg[base + d + 32] = f2bf(y1);
      }
    }
  } else {
    int kvh = nt - 16;
    for (int p = tid; p < 128 * 64; p += 256) {
      int srow = p & 127, d = p >> 7;
      int token = m0 + srow;
      int b = token >> 11, s = token & 2047;
      Vtg[((size_t)(b * NKVH + kvh) * HD + d) * SEQ + s] = f2bf(cbuf[srow * 64 + d]);
    }
  }
}

// ---------------- flash attention ----------------
// grid: (32, 56). blockIdx.x = q tile (64 rows), blockIdx.y = b*14+h.
__global__ __launch_bounds__(256) void k_attn(
    const ushort_t* __restrict__ Qg,
    const ushort_t* __restrict__ Kg,
    const ushort_t* __restrict__ Vtg,
    ushort_t* __restrict__ attn) {
  __shared__ ushort_t kbuf[64 * 64];
  __shared__ ushort_t vbuf[64 * 64];
  __shared__ ushort_t pbuf[4][16 * 64];

  const int qt = blockIdx.x;
  const int bh = blockIdx.y;
  const int b = bh / NQH, h = bh % NQH;
  const int kvh = h / (NQH / NKVH);
  const int tid = threadIdx.x;
  const int wave = tid >> 6, lane = tid & 63;
  const int l15 = lane & 15, quad = lane >> 4;
  const int q0 = qt * 64;

  const size_t qbase = ((size_t)bh * SEQ + q0 + wave * 16 + l15) * HD + quad * 8;
  bf16x8 qf0 = ldfrag(Qg + qbase);
  bf16x8 qf1 = ldfrag(Qg + qbase + 32);

  const size_t kbase = (size_t)(b * NKVH + kvh) * SEQ * HD;  // K [2048][64]
  const size_t vbase = (size_t)(b * NKVH + kvh) * HD * SEQ;  // Vt [64][2048]

  float m_i[4], l_i[4];
  f32x4 o[4];
  const f32x4 z4 = {0.f, 0.f, 0.f, 0.f};
#pragma unroll
  for (int r = 0; r < 4; ++r) { m_i[r] = -1e30f; l_i[r] = 0.f; }
#pragma unroll
  for (int nb = 0; nb < 4; ++nb) o[nb] = z4;

  const float cs = 0.125f * 1.44269504088896f;  // scale * log2(e)

  for (int jt = 0; jt < 32; ++jt) {
    const int s0 = jt * 64;
    __syncthreads();
#pragma unroll
    for (int i = 0; i < 2; ++i) {
      int c = wave * 128 + i * 64 + lane;
      async16(Kg + kbase + (size_t)(s0 + (c >> 3)) * HD + (c & 7) * 8,
              kbuf + (size_t)(wave * 128 + i * 64) * 8);
      async16(Vtg + vbase + (size_t)(c >> 3) * SEQ + s0 + (c & 7) * 8,
              vbuf + (size_t)(wave * 128 + i * 64) * 8);
    }
    __syncthreads();

    f32x4 sacc[4];
#pragma unroll
    for (int nb = 0; nb < 4; ++nb) {
      bf16x8 kf0 = ldfrag(kbuf + (nb * 16 + l15) * 64 + quad * 8);
      bf16x8 kf1 = ldfrag(kbuf + (nb * 16 + l15) * 64 + 32 + quad * 8);
      f32x4 t = z4;
      t = __builtin_amdgcn_mfma_f32_16x16x32_bf16(qf0, kf0, t, 0, 0, 0);
      t = __builtin_amdgcn_mfma_f32_16x16x32_bf16(qf1, kf1, t, 0, 0, 0);
      sacc[nb] = t;
    }

#pragma unroll
    for (int nb = 0; nb < 4; ++nb)
#pragma unroll
      for (int r = 0; r < 4; ++r) sacc[nb][r] *= cs;

    float alpha[4];
#pragma unroll
    for (int r = 0; r < 4; ++r) {
      float mx = fmaxf(fmaxf(sacc[0][r], sacc[1][r]), fmaxf(sacc[2][r], sacc[3][r]));
      mx = fmaxf(mx, __shfl_xor(mx, 1));
      mx = fmaxf(mx, __shfl_xor(mx, 2));
      mx = fmaxf(mx, __shfl_xor(mx, 4));
      mx = fmaxf(mx, __shfl_xor(mx, 8));
      float nmr = fmaxf(m_i[r], mx);
      alpha[r] = exp2f(m_i[r] - nmr);
      m_i[r] = nmr;
    }
#pragma unroll
    for (int r = 0; r < 4; ++r) {
      float sum = 0.f;
#pragma unroll
      for (int nb = 0; nb < 4; ++nb) {
        float pv = exp2f(sacc[nb][r] - m_i[r]);
        sacc[nb][r] = pv;
        sum += pv;
      }
      sum += __shfl_xor(sum, 1);
      sum += __shfl_xor(sum, 2);
      sum += __shfl_xor(sum, 4);
      sum += __shfl_xor(sum, 8);
      l_i[r] = l_i[r] * alpha[r] + sum;
    }
#pragma unroll
    for (int nb = 0; nb < 4; ++nb)
#pragma unroll
      for (int r = 0; r < 4; ++r) {
        o[nb][r] *= alpha[r];
        pbuf[wave][(quad * 4 + r) * 64 + nb * 16 + l15] = f2bf(sacc[nb][r]);
      }

    bf16x8 pf0 = ldfrag(&pbuf[wave][l15 * 64 + quad * 8]);
    bf16x8 pf1 = ldfrag(&pbuf[wave][l15 * 64 + 32 + quad * 8]);
#pragma unroll
    for (int nb = 0; nb < 4; ++nb) {
      bf16x8 vf0 = ldfrag(vbuf + (nb * 16 + l15) * 64 + quad * 8);
      bf16x8 vf1 = ldfrag(vbuf + (nb * 16 + l15) * 64 + 32 + quad * 8);
      o[nb] = __builtin_amdgcn_mfma_f32_16x16x32_bf16(pf0, vf0, o[nb], 0, 0, 0);
      o[nb] = __builtin_amdgcn_mfma_f32_16x16x32_bf16(pf1, vf1, o[nb], 0, 0, 0);
    }
  }

#pragma unroll
  for (int nb = 0; nb < 4; ++nb)
#pragma unroll
    for (int r = 0; r < 4; ++r) {
      int srow = q0 + wave * 16 + quad * 4 + r;
      float val = o[nb][r] / l_i[r];
      attn[(size_t)(b * SEQ + srow) * (NQH * HD) + h * HD + nb * 16 + l15] = f2bf(val);
    }
}

// ---------------- output projection ----------------
// grid: (14, 64)
__global__ __launch_bounds__(256) void k_oproj(
    const ushort_t* __restrict__ attn,
    const ushort_t* __restrict__ woT,
    float* __restrict__ out) {
  __shared__ ushort_t sa[128 * 32];
  __shared__ ushort_t sb[64 * 32];

  const int n0 = blockIdx.x * 64;
  const int m0 = blockIdx.y * 128;
  const int tid = threadIdx.x;
  const int wave = tid >> 6, lane = tid & 63;
  const int l15 = lane & 15, quad = lane >> 4;
  const int wm = wave >> 1, wn = wave & 1;

  f32x4 acc[4][2];
  const f32x4 z4 = {0.f, 0.f, 0.f, 0.f};
#pragma unroll
  for (int a = 0; a < 4; ++a)
#pragma unroll
    for (int b = 0; b < 2; ++b) acc[a][b] = z4;

  for (int kt = 0; kt < 28; ++kt) {
    const int k0 = kt * 32;
    __syncthreads();
#pragma unroll
    for (int i = 0; i < 2; ++i) {
      int c = wave * 128 + i * 64 + lane;
      async16(attn + (size_t)(m0 + (c >> 2)) * HIDDEN + k0 + (c & 3) * 8,
              sa + (size_t)(wave * 128 + i * 64) * 8);
    }
    {
      int c = wave * 64 + lane;
      async16(woT + (size_t)(n0 + (c >> 2)) * HIDDEN + k0 + (c & 3) * 8,
              sb + (size_t)(wave * 64) * 8);
    }
    __syncthreads();
    bf16x8 bf0 = ldfrag(sb + ((wn * 32 + l15) * 32 + quad * 8));
    bf16x8 bf1 = ldfrag(sb + ((wn * 32 + 16 + l15) * 32 + quad * 8));
#pragma unroll
    for (int mb = 0; mb < 4; ++mb) {
      bf16x8 af = ldfrag(sa + ((wm * 64 + mb * 16 + l15) * 32 + quad * 8));
      acc[mb][0] = __builtin_amdgcn_mfma_f32_16x16x32_bf16(af, bf0, acc[mb][0], 0, 0, 0);
      acc[mb][1] = __builtin_amdgcn_mfma_f32_16x16x32_bf16(af, bf1, acc[mb][1], 0, 0, 0);
    }
  }

#pragma unroll
  for (int mb = 0; mb < 4; ++mb)
#pragma unroll
    for (int nb = 0; nb < 2; ++nb)
#pragma unroll
      for (int r = 0; r < 4; ++r)
        out[(size_t)(m0 + wm * 64 + mb * 16 + quad * 4 + r) * HIDDEN +
            n0 + wn * 32 + nb * 16 + l15] = acc[mb][nb][r];
}

// ---------------- launch ----------------

extern "C" void kernel_launch(void* const* d_in, const int* in_sizes, int n_in,
                              void* d_out, int out_size, void* d_ws, size_t ws_size,
                              hipStream_t stream) {
  (void)in_sizes; (void)n_in; (void)out_size; (void)ws_size;
  const float* hidden = (const float*)d_in[0];
  const int* pos      = (const int*)d_in[1];
  const float* Wq     = (const float*)d_in[2];
  const float* Wk     = (const float*)d_in[3];
  const float* Wv     = (const float*)d_in[4];
  const float* Wo     = (const float*)d_in[5];
  float* out = (float*)d_out;

  char* ws = (char*)d_ws;
  ushort_t* hb   = (ushort_t*)(ws);               // 8192x896 bf16      (14,680,064 B)
  ushort_t* wqT  = (ushort_t*)(ws + 14680064);    // [896][896]         ( 1,605,632 B)
  ushort_t* wkT  = (ushort_t*)(ws + 16285696);    // [128][896]         (   229,376 B)
  ushort_t* wvT  = (ushort_t*)(ws + 16515072);    // [128][896]         (   229,376 B)
  ushort_t* woT  = (ushort_t*)(ws + 16744448);    // [896][896]         ( 1,605,632 B)
  ushort_t* Qg   = (ushort_t*)(ws + 18350080);    // [4][14][2048][64]  (14,680,064 B)
  ushort_t* Kg   = (ushort_t*)(ws + 33030144);    // [4][2][2048][64]   ( 2,097,152 B)
  ushort_t* Vtg  = (ushort_t*)(ws + 35127296);    // [4][2][64][2048]   ( 2,097,152 B)
  ushort_t* attn = (ushort_t*)(ws + 37224448);    // [8192][896]        (14,680,064 B)

  k_convert<<<7168, 256, 0, stream>>>(hidden, hb, 1835008);
  dim3 tb(32, 8);
  k_transpose<<<dim3(28, 28), tb, 0, stream>>>(Wq, wqT, 896, 896);
  k_transpose<<<dim3(4, 28), tb, 0, stream>>>(Wk, wkT, 896, 128);
  k_transpose<<<dim3(4, 28), tb, 0, stream>>>(Wv, wvT, 896, 128);
  k_transpose<<<dim3(28, 28), tb, 0, stream>>>(Wo, woT, 896, 896);

  k_qkv<<<dim3(18, 64), 256, 0, stream>>>(hb, wqT, wkT, wvT, pos, Qg, Kg, Vtg);
  k_attn<<<dim3(32, 56), 256, 0, stream>>>(Qg, Kg, Vtg, attn);
  k_oproj<<<dim3(14, 64), 256, 0, stream>>>(attn, woT, out);
}

// Round 2
// 269.792 us; speedup vs baseline: 1.6086x; 1.6086x over previous
//
#include <hip/hip_runtime.h>
#include <hip/hip_bf16.h>
#include <math.h>

typedef unsigned short ushort_t;
typedef __bf16 bf16x8 __attribute__((ext_vector_type(8)));
typedef float f32x4 __attribute__((ext_vector_type(4)));

#define HIDDEN 896
#define NQH 14
#define NKVH 2
#define HD 64
#define SEQ 2048
#define NBATCH 4

__device__ inline ushort_t f2bf(float x) {
  union { float f; unsigned u; } c; c.f = x;
  unsigned r = c.u + 0x7FFFu + ((c.u >> 16) & 1u);
  return (ushort_t)(r >> 16);
}

// pack two fp32 -> bf16x2 dword (round-half-up; bias < 0.5 ulp, fine at 2% tol)
__device__ inline unsigned pack2bf(float a, float b) {
  union { float f; unsigned u; } ca, cb; ca.f = a; cb.f = b;
  unsigned ua = ca.u + 0x8000u, ub = cb.u + 0x8000u;
  // v_perm: src1 bytes are idx 0-3, src0 bytes idx 4-7
  return __builtin_amdgcn_perm(ub, ua, 0x07060302);
}

__device__ inline bf16x8 ldfrag(const ushort_t* p) {
  return *reinterpret_cast<const bf16x8*>(p);
}

__device__ inline void async16(const ushort_t* g, ushort_t* l) {
  __builtin_amdgcn_global_load_lds(
      (const __attribute__((address_space(1))) void*)g,
      (__attribute__((address_space(3))) void*)l, 16, 0, 0);
}

// ---------------- prep kernels ----------------

__global__ void k_convert(const float* __restrict__ in, ushort_t* __restrict__ out, int n4) {
  int i = blockIdx.x * blockDim.x + threadIdx.x;
  if (i >= n4) return;
  float4 v = reinterpret_cast<const float4*>(in)[i];
  ushort4 o;
  o.x = f2bf(v.x); o.y = f2bf(v.y); o.z = f2bf(v.z); o.w = f2bf(v.w);
  reinterpret_cast<ushort4*>(out)[i] = o;
}

// in [K][N] f32 -> out [N][K] bf16
__global__ void k_transpose(const float* __restrict__ in, ushort_t* __restrict__ out, int K, int N) {
  __shared__ float tile[32][33];
  int k0 = blockIdx.y * 32, n0 = blockIdx.x * 32;
  for (int r = threadIdx.y; r < 32; r += 8) {
    int k = k0 + r, n = n0 + threadIdx.x;
    tile[r][threadIdx.x] = (k < K && n < N) ? in[(size_t)k * N + n] : 0.f;
  }
  __syncthreads();
  for (int r = threadIdx.y; r < 32; r += 8) {
    int n = n0 + r, k = k0 + threadIdx.x;
    if (n < N && k < K) out[(size_t)n * K + k] = f2bf(tile[threadIdx.x][r]);
  }
}

// ---------------- QKV projection + RoPE ----------------
// grid: (18, 64). nt 0..13 -> Q head nt; 14..15 -> K kvh; 16..17 -> V kvh.
__global__ __launch_bounds__(256) void k_qkv(
    const ushort_t* __restrict__ hb,
    const ushort_t* __restrict__ wqT,
    const ushort_t* __restrict__ wkT,
    const ushort_t* __restrict__ wvT,
    const int* __restrict__ pos_ids,
    ushort_t* __restrict__ Qg,
    ushort_t* __restrict__ Kg,
    ushort_t* __restrict__ Vtg) {
  __shared__ ushort_t sa[128 * 32];
  __shared__ ushort_t sb[64 * 32];
  __shared__ float cbuf[128 * 64];

  const int nt = blockIdx.x;
  const int m0 = blockIdx.y * 128;
  const int tid = threadIdx.x;
  const int wave = tid >> 6, lane = tid & 63;
  const int l15 = lane & 15, quad = lane >> 4;
  const int wm = wave >> 1, wn = wave & 1;

  const ushort_t* wsrc; int nsrc0;
  if (nt < 14)      { wsrc = wqT; nsrc0 = nt * 64; }
  else if (nt < 16) { wsrc = wkT; nsrc0 = (nt - 14) * 64; }
  else              { wsrc = wvT; nsrc0 = (nt - 16) * 64; }

  f32x4 acc[4][2];
  const f32x4 z4 = {0.f, 0.f, 0.f, 0.f};
#pragma unroll
  for (int a = 0; a < 4; ++a)
#pragma unroll
    for (int b = 0; b < 2; ++b) acc[a][b] = z4;

  for (int kt = 0; kt < 28; ++kt) {
    const int k0 = kt * 32;
    __syncthreads();
#pragma unroll
    for (int i = 0; i < 2; ++i) {
      int c = wave * 128 + i * 64 + lane;
      async16(hb + (size_t)(m0 + (c >> 2)) * HIDDEN + k0 + (c & 3) * 8,
              sa + (size_t)(wave * 128 + i * 64) * 8);
    }
    {
      int c = wave * 64 + lane;
      async16(wsrc + (size_t)(nsrc0 + (c >> 2)) * HIDDEN + k0 + (c & 3) * 8,
              sb + (size_t)(wave * 64) * 8);
    }
    __syncthreads();
    bf16x8 bf0 = ldfrag(sb + ((wn * 32 + l15) * 32 + quad * 8));
    bf16x8 bf1 = ldfrag(sb + ((wn * 32 + 16 + l15) * 32 + quad * 8));
#pragma unroll
    for (int mb = 0; mb < 4; ++mb) {
      bf16x8 af = ldfrag(sa + ((wm * 64 + mb * 16 + l15) * 32 + quad * 8));
      acc[mb][0] = __builtin_amdgcn_mfma_f32_16x16x32_bf16(af, bf0, acc[mb][0], 0, 0, 0);
      acc[mb][1] = __builtin_amdgcn_mfma_f32_16x16x32_bf16(af, bf1, acc[mb][1], 0, 0, 0);
    }
  }

  __syncthreads();
#pragma unroll
  for (int mb = 0; mb < 4; ++mb)
#pragma unroll
    for (int nb = 0; nb < 2; ++nb)
#pragma unroll
      for (int r = 0; r < 4; ++r)
        cbuf[(wm * 64 + mb * 16 + quad * 4 + r) * 64 + wn * 32 + nb * 16 + l15] = acc[mb][nb][r];
  __syncthreads();

  if (nt < 16) {
    // RoPE + store (Q or K). Q additionally pre-scaled by 0.125*log2(e)
    const float cs = 0.125f * 1.44269504088896f;
    for (int p = tid; p < 128 * 32; p += 256) {
      int row = p >> 5, d = p & 31;
      int token = m0 + row;
      int b = token >> 11, s = token & 2047;
      int pos = pos_ids[token];
      float x0 = cbuf[row * 64 + d];
      float x1 = cbuf[row * 64 + d + 32];
      float inv = exp2f(-(float)d * 0.41524101186092596f);
      float ang = (float)pos * inv;
      float sn, cn;
      sincosf(ang, &sn, &cn);
      float y0 = x0 * cn - x1 * sn;
      float y1 = x1 * cn + x0 * sn;
      if (nt < 14) {
        size_t base = ((size_t)(b * NQH + nt) * SEQ + s) * HD;
        Qg[base + d]      = f2bf(y0 * cs);
        Qg[base + d + 32] = f2bf(y1 * cs);
      } else {
        size_t base = ((size_t)(b * NKVH + (nt - 14)) * SEQ + s) * HD;
        Kg[base + d]      = f2bf(y0);
        Kg[base + d + 32] = f2bf(y1);
      }
    }
  } else {
    int kvh = nt - 16;
    for (int p = tid; p < 128 * 64; p += 256) {
      int srow = p & 127, d = p >> 7;
      int token = m0 + srow;
      int b = token >> 11, s = token & 2047;
      Vtg[((size_t)(b * NKVH + kvh) * HD + d) * SEQ + s] = f2bf(cbuf[srow * 64 + d]);
    }
  }
}

// ---------------- flash attention (S^T orientation, swizzled LDS) ----------------
// grid: (16, 56). blockIdx.x = q tile (128 rows), blockIdx.y = b*14+h.
// Each wave owns 32 q rows (2 sub-tiles of 16).
__global__ __launch_bounds__(256) void k_attn(
    const ushort_t* __restrict__ Qg,
    const ushort_t* __restrict__ Kg,
    const ushort_t* __restrict__ Vtg,
    ushort_t* __restrict__ attn) {
  // K/V tiles: 64 rows x 8 chunks(16B); chunk c of row r at slot r*8 + (c^(r&7))
  __shared__ ushort_t kbuf[64 * 64];
  __shared__ ushort_t vbuf[64 * 64];
  // per-wave P buffer: 32 rows x 72 ushorts (144B = 9x16B rows, phase-optimal)
  __shared__ ushort_t pbuf[4][32 * 72];

  const int qt = blockIdx.x;
  const int bh = blockIdx.y;
  const int b = bh / NQH, h = bh % NQH;
  const int kvh = h / (NQH / NKVH);
  const int tid = threadIdx.x;
  const int wave = tid >> 6, lane = tid & 63;
  const int l15 = lane & 15, quad = lane >> 4;
  const int q0 = qt * 128;

  // Q fragments (pre-scaled by 0.125*log2e in k_qkv): B-operand layout
  bf16x8 qf[2][2];
#pragma unroll
  for (int qs = 0; qs < 2; ++qs) {
    const size_t qb = ((size_t)bh * SEQ + q0 + wave * 32 + qs * 16 + l15) * HD + quad * 8;
    qf[qs][0] = ldfrag(Qg + qb);
    qf[qs][1] = ldfrag(Qg + qb + 32);
  }

  const size_t kbase = (size_t)(b * NKVH + kvh) * SEQ * HD;  // K [2048][64]
  const size_t vbase = (size_t)(b * NKVH + kvh) * HD * SEQ;  // Vt [64][2048]

  float l_acc[2] = {0.f, 0.f};
  f32x4 o[2][4];
  const f32x4 z4 = {0.f, 0.f, 0.f, 0.f};
#pragma unroll
  for (int qs = 0; qs < 2; ++qs)
#pragma unroll
    for (int nb = 0; nb < 4; ++nb) o[qs][nb] = z4;

  ushort_t* pw = pbuf[wave];

  for (int jt = 0; jt < 32; ++jt) {
    const int s0 = jt * 64;
    __syncthreads();
#pragma unroll
    for (int i = 0; i < 2; ++i) {
      int s = i * 256 + tid;           // chunk slot 0..511
      int row = s >> 3;
      int c = (s & 7) ^ (row & 7);     // swizzled source chunk
      int sbase = i * 256 + wave * 64; // wave-uniform slot base
      async16(Kg + kbase + (size_t)(s0 + row) * HD + c * 8, kbuf + sbase * 8);
      async16(Vtg + vbase + (size_t)row * SEQ + s0 + c * 8, vbuf + sbase * 8);
    }
    __syncthreads();

    // S^T = K x Q^T : A = K rows (m=key), B = Q (n=q). p = exp2(s), no max.
    float lsum[2] = {0.f, 0.f};
#pragma unroll
    for (int nb = 0; nb < 4; ++nb) {
      int row = nb * 16 + l15;
      int sw = row & 7;
      bf16x8 kf0 = ldfrag(kbuf + (row * 8 + (quad ^ sw)) * 8);
      bf16x8 kf1 = ldfrag(kbuf + (row * 8 + ((4 + quad) ^ sw)) * 8);
#pragma unroll
      for (int qs = 0; qs < 2; ++qs) {
        f32x4 t = z4;
        t = __builtin_amdgcn_mfma_f32_16x16x32_bf16(kf0, qf[qs][0], t, 0, 0, 0);
        t = __builtin_amdgcn_mfma_f32_16x16x32_bf16(kf1, qf[qs][1], t, 0, 0, 0);
        float p0 = __builtin_amdgcn_exp2f(t[0]);
        float p1 = __builtin_amdgcn_exp2f(t[1]);
        float p2 = __builtin_amdgcn_exp2f(t[2]);
        float p3 = __builtin_amdgcn_exp2f(t[3]);
        lsum[qs] += (p0 + p1) + (p2 + p3);
        uint2 d;
        d.x = pack2bf(p0, p1);
        d.y = pack2bf(p2, p3);
        // P[q][k]: row q = qs*16+l15, cols k = nb*16+quad*4 .. +3
        *reinterpret_cast<uint2*>(pw + (qs * 16 + l15) * 72 + nb * 16 + quad * 4) = d;
      }
    }
#pragma unroll
    for (int qs = 0; qs < 2; ++qs) {
      float s = lsum[qs];
      s += __shfl_xor(s, 16);
      s += __shfl_xor(s, 32);
      l_acc[qs] += s;
    }

    // PV: A = P (rows q), B = V^T tile (n = d)
    bf16x8 pf[2][2];
#pragma unroll
    for (int qs = 0; qs < 2; ++qs) {
      pf[qs][0] = ldfrag(pw + (qs * 16 + l15) * 72 + quad * 8);
      pf[qs][1] = ldfrag(pw + (qs * 16 + l15) * 72 + 32 + quad * 8);
    }
#pragma unroll
    for (int nb = 0; nb < 4; ++nb) {
      int row = nb * 16 + l15;  // d
      int sw = row & 7;
      bf16x8 vf0 = ldfrag(vbuf + (row * 8 + (quad ^ sw)) * 8);
      bf16x8 vf1 = ldfrag(vbuf + (row * 8 + ((4 + quad) ^ sw)) * 8);
#pragma unroll
      for (int qs = 0; qs < 2; ++qs) {
        o[qs][nb] = __builtin_amdgcn_mfma_f32_16x16x32_bf16(pf[qs][0], vf0, o[qs][nb], 0, 0, 0);
        o[qs][nb] = __builtin_amdgcn_mfma_f32_16x16x32_bf16(pf[qs][1], vf1, o[qs][nb], 0, 0, 0);
      }
    }
  }

  // epilogue: O C-layout lane(quad,l15): q = qs*16+quad*4+r, d = nb*16+l15
#pragma unroll
  for (int qs = 0; qs < 2; ++qs) {
    float il = 1.0f / l_acc[qs];  // valid at lane l15 (q = qs*16+l15)
#pragma unroll
    for (int r = 0; r < 4; ++r) {
      float inv = __shfl(il, quad * 4 + r);
      int qg = q0 + wave * 32 + qs * 16 + quad * 4 + r;
#pragma unroll
      for (int nb = 0; nb < 4; ++nb) {
        float val = o[qs][nb][r] * inv;
        attn[(size_t)(b * SEQ + qg) * (NQH * HD) + h * HD + nb * 16 + l15] = f2bf(val);
      }
    }
  }
}

// ---------------- output projection ----------------
// grid: (14, 64)
__global__ __launch_bounds__(256) void k_oproj(
    const ushort_t* __restrict__ attn,
    const ushort_t* __restrict__ woT,
    float* __restrict__ out) {
  __shared__ ushort_t sa[128 * 32];
  __shared__ ushort_t sb[64 * 32];

  const int n0 = blockIdx.x * 64;
  const int m0 = blockIdx.y * 128;
  const int tid = threadIdx.x;
  const int wave = tid >> 6, lane = tid & 63;
  const int l15 = lane & 15, quad = lane >> 4;
  const int wm = wave >> 1, wn = wave & 1;

  f32x4 acc[4][2];
  const f32x4 z4 = {0.f, 0.f, 0.f, 0.f};
#pragma unroll
  for (int a = 0; a < 4; ++a)
#pragma unroll
    for (int b = 0; b < 2; ++b) acc[a][b] = z4;

  for (int kt = 0; kt < 28; ++kt) {
    const int k0 = kt * 32;
    __syncthreads();
#pragma unroll
    for (int i = 0; i < 2; ++i) {
      int c = wave * 128 + i * 64 + lane;
      async16(attn + (size_t)(m0 + (c >> 2)) * HIDDEN + k0 + (c & 3) * 8,
              sa + (size_t)(wave * 128 + i * 64) * 8);
    }
    {
      int c = wave * 64 + lane;
      async16(woT + (size_t)(n0 + (c >> 2)) * HIDDEN + k0 + (c & 3) * 8,
              sb + (size_t)(wave * 64) * 8);
    }
    __syncthreads();
    bf16x8 bf0 = ldfrag(sb + ((wn * 32 + l15) * 32 + quad * 8));
    bf16x8 bf1 = ldfrag(sb + ((wn * 32 + 16 + l15) * 32 + quad * 8));
#pragma unroll
    for (int mb = 0; mb < 4; ++mb) {
      bf16x8 af = ldfrag(sa + ((wm * 64 + mb * 16 + l15) * 32 + quad * 8));
      acc[mb][0] = __builtin_amdgcn_mfma_f32_16x16x32_bf16(af, bf0, acc[mb][0], 0, 0, 0);
      acc[mb][1] = __builtin_amdgcn_mfma_f32_16x16x32_bf16(af, bf1, acc[mb][1], 0, 0, 0);
    }
  }

#pragma unroll
  for (int mb = 0; mb < 4; ++mb)
#pragma unroll
    for (int nb = 0; nb < 2; ++nb)
#pragma unroll
      for (int r = 0; r < 4; ++r)
        out[(size_t)(m0 + wm * 64 + mb * 16 + quad * 4 + r) * HIDDEN +
            n0 + wn * 32 + nb * 16 + l15] = acc[mb][nb][r];
}

// ---------------- launch ----------------

extern "C" void kernel_launch(void* const* d_in, const int* in_sizes, int n_in,
                              void* d_out, int out_size, void* d_ws, size_t ws_size,
                              hipStream_t stream) {
  (void)in_sizes; (void)n_in; (void)out_size; (void)ws_size;
  const float* hidden = (const float*)d_in[0];
  const int* pos      = (const int*)d_in[1];
  const float* Wq     = (const float*)d_in[2];
  const float* Wk     = (const float*)d_in[3];
  const float* Wv     = (const float*)d_in[4];
  const float* Wo     = (const float*)d_in[5];
  float* out = (float*)d_out;

  char* ws = (char*)d_ws;
  ushort_t* hb   = (ushort_t*)(ws);               // 8192x896 bf16      (14,680,064 B)
  ushort_t* wqT  = (ushort_t*)(ws + 14680064);    // [896][896]         ( 1,605,632 B)
  ushort_t* wkT  = (ushort_t*)(ws + 16285696);    // [128][896]         (   229,376 B)
  ushort_t* wvT  = (ushort_t*)(ws + 16515072);    // [128][896]         (   229,376 B)
  ushort_t* woT  = (ushort_t*)(ws + 16744448);    // [896][896]         ( 1,605,632 B)
  ushort_t* Qg   = (ushort_t*)(ws + 18350080);    // [4][14][2048][64]  (14,680,064 B)
  ushort_t* Kg   = (ushort_t*)(ws + 33030144);    // [4][2][2048][64]   ( 2,097,152 B)
  ushort_t* Vtg  = (ushort_t*)(ws + 35127296);    // [4][2][64][2048]   ( 2,097,152 B)
  ushort_t* attn = (ushort_t*)(ws + 37224448);    // [8192][896]        (14,680,064 B)

  k_convert<<<7168, 256, 0, stream>>>(hidden, hb, 1835008);
  dim3 tb(32, 8);
  k_transpose<<<dim3(28, 28), tb, 0, stream>>>(Wq, wqT, 896, 896);
  k_transpose<<<dim3(4, 28), tb, 0, stream>>>(Wk, wkT, 896, 128);
  k_transpose<<<dim3(4, 28), tb, 0, stream>>>(Wv, wvT, 896, 128);
  k_transpose<<<dim3(28, 28), tb, 0, stream>>>(Wo, woT, 896, 896);

  k_qkv<<<dim3(18, 64), 256, 0, stream>>>(hb, wqT, wkT, wvT, pos, Qg, Kg, Vtg);
  k_attn<<<dim3(16, 56), 256, 0, stream>>>(Qg, Kg, Vtg, attn);
  k_oproj<<<dim3(14, 64), 256, 0, stream>>>(attn, woT, out);
}